// Round 1
// baseline (233.313 us; speedup 1.0000x reference)
//
#include <hip/hip_runtime.h>

#define S_LEN 2048
#define BATCH 4
#define DMODEL 512
#define NHEAD 8
#define HDIM 64
#define ROWS (BATCH * S_LEN) /* 8192 */

using short8 = __attribute__((ext_vector_type(8))) short;
using f32x4  = __attribute__((ext_vector_type(4))) float;

__device__ __forceinline__ unsigned short f2bf(float f) {
  unsigned int u = __builtin_bit_cast(unsigned int, f);
  u += 0x7fffu + ((u >> 16) & 1u);
  return (unsigned short)(u >> 16);
}
__device__ __forceinline__ float bf2f(unsigned short h) {
  unsigned int u = ((unsigned int)h) << 16;
  return __builtin_bit_cast(float, u);
}

// ---------------- fp32 -> bf16 convert, 8 elems / thread ----------------
__global__ __launch_bounds__(256) void cvt_bf16_kernel(const float* __restrict__ x,
                                                       unsigned short* __restrict__ xb,
                                                       int n) {
  int t = blockIdx.x * 256 + threadIdx.x;
  int base = t * 8;
  if (base >= n) return;
  float4 f0 = *(const float4*)(x + base);
  float4 f1 = *(const float4*)(x + base + 4);
  uint4 o;
  o.x = (unsigned)f2bf(f0.x) | ((unsigned)f2bf(f0.y) << 16);
  o.y = (unsigned)f2bf(f0.z) | ((unsigned)f2bf(f0.w) << 16);
  o.z = (unsigned)f2bf(f1.x) | ((unsigned)f2bf(f1.y) << 16);
  o.w = (unsigned)f2bf(f1.z) | ((unsigned)f2bf(f1.w) << 16);
  *(uint4*)(xb + base) = o;
}

// ---------------- W[k][n] fp32 -> WT[n][k] bf16 (512x512) ----------------
__global__ void transpose_w_kernel(const float* __restrict__ W,
                                   unsigned short* __restrict__ WT) {
  __shared__ float t[32][33];
  const int tx = threadIdx.x, ty = threadIdx.y; // 32 x 8
  const int x0 = blockIdx.x * 32, y0 = blockIdx.y * 32;
#pragma unroll
  for (int r = 0; r < 4; r++)
    t[ty + 8 * r][tx] = W[(size_t)(y0 + ty + 8 * r) * DMODEL + x0 + tx];
  __syncthreads();
#pragma unroll
  for (int r = 0; r < 4; r++)
    WT[(size_t)(x0 + ty + 8 * r) * DMODEL + y0 + tx] = f2bf(t[tx][ty + 8 * r]);
}

// ---------------- GEMM: C[m][n] = sum_k A[m][k] * Bt[n][k] + bias ----------------
// A: [M][K] bf16, Bt: [N][K] bf16. Tile 128x64, BK=32, 256 thr (4 waves, 2x2).
template <int OUT_F32, int BIAS_M>
__global__ __launch_bounds__(256) void gemm_bt_kernel(const unsigned short* __restrict__ A,
                                                      const unsigned short* __restrict__ Bt,
                                                      const float* __restrict__ bias,
                                                      void* __restrict__ Cout,
                                                      int M, int N, int K) {
  (void)M;
  constexpr int LDT = 40; // pad 32 -> 40 bf16: 2-way-max LDS bank aliasing
  __shared__ unsigned short As[128][LDT];
  __shared__ unsigned short Bs[64][LDT];
  const int tid = threadIdx.x;
  const int m0 = blockIdx.y * 128, n0 = blockIdx.x * 64;
  const int wave = tid >> 6, lane = tid & 63;
  const int wr = wave >> 1, wc = wave & 1;
  const int lm = lane & 15, lq = lane >> 4;
  const int srow = tid >> 2, skc = (tid & 3) * 8;
  f32x4 acc[4][2] = {};
  for (int k0 = 0; k0 < K; k0 += 32) {
    uint4 a0 = *(const uint4*)(A + (size_t)(m0 + srow) * K + k0 + skc);
    uint4 a1 = *(const uint4*)(A + (size_t)(m0 + srow + 64) * K + k0 + skc);
    uint4 b0 = *(const uint4*)(Bt + (size_t)(n0 + srow) * K + k0 + skc);
    __syncthreads();
    *(uint4*)&As[srow][skc] = a0;
    *(uint4*)&As[srow + 64][skc] = a1;
    *(uint4*)&Bs[srow][skc] = b0;
    __syncthreads();
    short8 af[4], bfr[2];
#pragma unroll
    for (int mi = 0; mi < 4; mi++)
      af[mi] = *(const short8*)&As[wr * 64 + mi * 16 + lm][lq * 8];
#pragma unroll
    for (int ni = 0; ni < 2; ni++)
      bfr[ni] = *(const short8*)&Bs[wc * 32 + ni * 16 + lm][lq * 8];
#pragma unroll
    for (int mi = 0; mi < 4; mi++)
#pragma unroll
      for (int ni = 0; ni < 2; ni++)
        acc[mi][ni] = __builtin_amdgcn_mfma_f32_16x16x32_bf16(af[mi], bfr[ni], acc[mi][ni], 0, 0, 0);
  }
#pragma unroll
  for (int mi = 0; mi < 4; mi++) {
#pragma unroll
    for (int ni = 0; ni < 2; ni++) {
      const int row = m0 + wr * 64 + mi * 16 + lq * 4;
      const int col = n0 + wc * 32 + ni * 16 + lm;
#pragma unroll
      for (int r = 0; r < 4; r++) {
        float v = acc[mi][ni][r] + (BIAS_M ? bias[row + r] : bias[col]);
        if (OUT_F32)
          ((float*)Cout)[(size_t)(row + r) * N + col] = v;
        else
          ((unsigned short*)Cout)[(size_t)(row + r) * N + col] = f2bf(v);
      }
    }
  }
}

// ---------------- vsum[b][n] = sum_j Vt[n][b*S+j] (for all-masked fallback) -------
__global__ __launch_bounds__(256) void vsum_kernel(const unsigned short* __restrict__ Vt,
                                                   float* __restrict__ vs) {
  const int wid = blockIdx.x * 4 + (threadIdx.x >> 6);
  const int lane = threadIdx.x & 63;
  const int b = wid >> 9, n = wid & 511;
  const unsigned short* row = Vt + (size_t)n * ROWS + b * S_LEN;
  float s = 0.f;
#pragma unroll
  for (int it = 0; it < 4; it++) {
    uint4 v = *(const uint4*)(row + it * 512 + lane * 8);
    unsigned int w[4] = {v.x, v.y, v.z, v.w};
#pragma unroll
    for (int e = 0; e < 4; e++) {
      s += bf2f((unsigned short)(w[e] & 0xffffu));
      s += bf2f((unsigned short)(w[e] >> 16));
    }
  }
#pragma unroll
  for (int off = 1; off < 64; off <<= 1) s += __shfl_xor(s, off, 64);
  if (lane == 0) vs[(size_t)b * DMODEL + n] = s;
}

// ---------------- banded flash attention: 1 wave per (b, h, 16 queries) ----------
// Q,K: [B*S][512] bf16 (col = h*64+d). Vt: [512][B*S] bf16 (row = h*64+d).
__global__ __launch_bounds__(64) void attn_kernel(const unsigned short* __restrict__ Q,
                                                  const unsigned short* __restrict__ K,
                                                  const unsigned short* __restrict__ Vt,
                                                  const int* __restrict__ x_len,
                                                  const float* __restrict__ vsum,
                                                  unsigned short* __restrict__ ctx) {
  __shared__ unsigned short Ps[16][40];
  const int bid = blockIdx.x;
  const int b = bid >> 10;          // 8 heads * 128 qtiles
  const int h = (bid >> 7) & 7;
  const int i0 = (bid & 127) << 4;
  const int lane = threadIdx.x;
  const int lm = lane & 15, lq = lane >> 4;
  const int xlen = x_len[b];

  const size_t qoff = (size_t)(b * S_LEN + i0 + lm) * DMODEL + h * HDIM + lq * 8;
  const short8 aq0 = *(const short8*)(Q + qoff);
  const short8 aq1 = *(const short8*)(Q + qoff + 32);

  f32x4 oacc[4] = {};
  float mrow[4] = {-1e30f, -1e30f, -1e30f, -1e30f};
  float lrow[4] = {0.f, 0.f, 0.f, 0.f};

  for (int kt = 0; kt < 9; kt++) {
    const int jt0 = i0 - 128 + kt * 32;
    f32x4 sv[2];
#pragma unroll
    for (int sub = 0; sub < 2; sub++) {
      const int jr = jt0 + sub * 16 + lm;
      const int jrc = min(max(jr, 0), S_LEN - 1);
      const size_t koff = (size_t)(b * S_LEN + jrc) * DMODEL + h * HDIM + lq * 8;
      const short8 bk0 = *(const short8*)(K + koff);
      const short8 bk1 = *(const short8*)(K + koff + 32);
      f32x4 s = {};
      s = __builtin_amdgcn_mfma_f32_16x16x32_bf16(aq0, bk0, s, 0, 0, 0);
      s = __builtin_amdgcn_mfma_f32_16x16x32_bf16(aq1, bk1, s, 0, 0, 0);
      sv[sub] = s;
    }
#pragma unroll
    for (int sub = 0; sub < 2; sub++) {
      const int j = jt0 + sub * 16 + lm;
      const bool jv = (j >= 0) && (j < xlen);
#pragma unroll
      for (int r = 0; r < 4; r++) {
        const int i = i0 + lq * 4 + r;
        const bool ok = jv && (j - i <= 128) && (i - j <= 128);
        sv[sub][r] = ok ? sv[sub][r] * 0.125f : -1e30f;
      }
    }
    float alpha[4], p0[4], p1[4];
#pragma unroll
    for (int r = 0; r < 4; r++) {
      float mx = fmaxf(sv[0][r], sv[1][r]);
#pragma unroll
      for (int off = 1; off < 16; off <<= 1) mx = fmaxf(mx, __shfl_xor(mx, off, 64));
      const float mn = fmaxf(mrow[r], mx);
      alpha[r] = __expf(mrow[r] - mn);
      mrow[r] = mn;
      p0[r] = (sv[0][r] > -1e29f) ? __expf(sv[0][r] - mn) : 0.f;
      p1[r] = (sv[1][r] > -1e29f) ? __expf(sv[1][r] - mn) : 0.f;
      float rs = p0[r] + p1[r];
#pragma unroll
      for (int off = 1; off < 16; off <<= 1) rs += __shfl_xor(rs, off, 64);
      lrow[r] = lrow[r] * alpha[r] + rs;
    }
    __syncthreads(); // protect Ps reads of previous tile
#pragma unroll
    for (int r = 0; r < 4; r++) {
      Ps[lq * 4 + r][lm] = f2bf(p0[r]);
      Ps[lq * 4 + r][16 + lm] = f2bf(p1[r]);
    }
    __syncthreads();
    const short8 pf = *(const short8*)&Ps[lm][lq * 8]; // A-layout P
    const int jv0 = jt0 + lq * 8;
    const int jvc = min(max(jv0, 0), S_LEN - 8); // clamped reads have P==0
#pragma unroll
    for (int dt = 0; dt < 4; dt++) {
#pragma unroll
      for (int r = 0; r < 4; r++) oacc[dt][r] *= alpha[r];
      const size_t voff = (size_t)(h * HDIM + dt * 16 + lm) * ROWS + b * S_LEN + jvc;
      const short8 bv = *(const short8*)(Vt + voff);
      oacc[dt] = __builtin_amdgcn_mfma_f32_16x16x32_bf16(pf, bv, oacc[dt], 0, 0, 0);
    }
  }
#pragma unroll
  for (int r = 0; r < 4; r++) {
    const int i = i0 + lq * 4 + r;
    const size_t obase = (size_t)(b * S_LEN + i) * DMODEL + h * HDIM;
    if (lrow[r] > 0.f) {
      const float inv = 1.f / lrow[r];
#pragma unroll
      for (int dt = 0; dt < 4; dt++)
        ctx[obase + dt * 16 + lm] = f2bf(oacc[dt][r] * inv);
    } else {
      // all keys masked -> reference softmax is exactly uniform over ALL 2048 keys
#pragma unroll
      for (int dt = 0; dt < 4; dt++)
        ctx[obase + dt * 16 + lm] =
            f2bf(vsum[(size_t)b * DMODEL + h * HDIM + dt * 16 + lm] * (1.f / 2048.f));
    }
  }
}

extern "C" void kernel_launch(void* const* d_in, const int* in_sizes, int n_in,
                              void* d_out, int out_size, void* d_ws, size_t ws_size,
                              hipStream_t stream) {
  (void)in_sizes; (void)n_in; (void)out_size; (void)ws_size;
  const float* x  = (const float*)d_in[0];
  const float* Wq = (const float*)d_in[1];
  const float* bq = (const float*)d_in[2];
  const float* Wk = (const float*)d_in[3];
  const float* bk = (const float*)d_in[4];
  const float* Wv = (const float*)d_in[5];
  const float* bv = (const float*)d_in[6];
  const float* Wo = (const float*)d_in[7];
  const float* bo = (const float*)d_in[8];
  const int* x_len = (const int*)d_in[9];

  char* ws = (char*)d_ws;
  const size_t MB = 1024 * 1024;
  unsigned short* xb  = (unsigned short*)(ws + 0 * MB);   // 8 MB  [8192][512]
  unsigned short* Qb  = (unsigned short*)(ws + 8 * MB);   // 8 MB  [8192][512]
  unsigned short* Kb  = (unsigned short*)(ws + 16 * MB);  // 8 MB  [8192][512]
  unsigned short* Vt  = (unsigned short*)(ws + 24 * MB);  // 8 MB  [512][8192]
  unsigned short* Cx  = (unsigned short*)(ws + 32 * MB);  // 8 MB  [8192][512]
  unsigned short* WqT = (unsigned short*)(ws + 40 * MB);
  unsigned short* WkT = (unsigned short*)(ws + 40 * MB + 512 * 1024);
  unsigned short* WvT = (unsigned short*)(ws + 41 * MB);
  unsigned short* WoT = (unsigned short*)(ws + 41 * MB + 512 * 1024);
  float* vsum         = (float*)(ws + 42 * MB); // 8 KB

  cvt_bf16_kernel<<<(ROWS * DMODEL) / 2048, 256, 0, stream>>>(x, xb, ROWS * DMODEL);
  dim3 tb(32, 8), tg(16, 16);
  transpose_w_kernel<<<tg, tb, 0, stream>>>(Wq, WqT);
  transpose_w_kernel<<<tg, tb, 0, stream>>>(Wk, WkT);
  transpose_w_kernel<<<tg, tb, 0, stream>>>(Wv, WvT);
  transpose_w_kernel<<<tg, tb, 0, stream>>>(Wo, WoT);

  // Q, K: [8192][512] bf16
  gemm_bt_kernel<0, 0><<<dim3(DMODEL / 64, ROWS / 128), 256, 0, stream>>>(
      xb, WqT, bq, Qb, ROWS, DMODEL, DMODEL);
  gemm_bt_kernel<0, 0><<<dim3(DMODEL / 64, ROWS / 128), 256, 0, stream>>>(
      xb, WkT, bk, Kb, ROWS, DMODEL, DMODEL);
  // V transposed: C[feature][row] = sum_k WvT[feature][k] * xb[row][k] + bv[feature]
  gemm_bt_kernel<0, 1><<<dim3(ROWS / 64, DMODEL / 128), 256, 0, stream>>>(
      WvT, xb, bv, Vt, DMODEL, ROWS, DMODEL);
  vsum_kernel<<<512, 256, 0, stream>>>(Vt, vsum);
  attn_kernel<<<BATCH * NHEAD * (S_LEN / 16), 64, 0, stream>>>(Qb, Kb, Vt, x_len, vsum, Cx);
  // out = ctx @ Wo + bo  (fp32 out)
  gemm_bt_kernel<1, 0><<<dim3(DMODEL / 64, ROWS / 128), 256, 0, stream>>>(
      Cx, WoT, bo, (float*)d_out, ROWS, DMODEL, DMODEL);
}

// Round 3
// 168.039 us; speedup vs baseline: 1.3884x; 1.3884x over previous
//
#include <hip/hip_runtime.h>

#define S_LEN 2048
#define BATCH 4
#define DMODEL 512
#define NHEAD 8
#define HDIM 64
#define ROWS (BATCH * S_LEN) /* 8192 */

using short8 = __attribute__((ext_vector_type(8))) short;
using f32x4  = __attribute__((ext_vector_type(4))) float;

__device__ __forceinline__ unsigned short f2bf(float f) {
  unsigned int u = __builtin_bit_cast(unsigned int, f);
  u += 0x7fffu + ((u >> 16) & 1u);
  return (unsigned short)(u >> 16);
}
__device__ __forceinline__ float bf2f(unsigned short h) {
  unsigned int u = ((unsigned int)h) << 16;
  return __builtin_bit_cast(float, u);
}
__device__ __forceinline__ void glds16(const void* g, void* l) {
  __builtin_amdgcn_global_load_lds((const __attribute__((address_space(1))) unsigned*)g,
                                   (__attribute__((address_space(3))) unsigned*)l, 16, 0, 0);
}

// ---------------- fp32 -> bf16 convert, 8 elems / thread ----------------
__global__ __launch_bounds__(256) void cvt_bf16_kernel(const float* __restrict__ x,
                                                       unsigned short* __restrict__ xb,
                                                       int n) {
  int t = blockIdx.x * 256 + threadIdx.x;
  int base = t * 8;
  if (base >= n) return;
  float4 f0 = *(const float4*)(x + base);
  float4 f1 = *(const float4*)(x + base + 4);
  uint4 o;
  o.x = (unsigned)f2bf(f0.x) | ((unsigned)f2bf(f0.y) << 16);
  o.y = (unsigned)f2bf(f0.z) | ((unsigned)f2bf(f0.w) << 16);
  o.z = (unsigned)f2bf(f1.x) | ((unsigned)f2bf(f1.y) << 16);
  o.w = (unsigned)f2bf(f1.z) | ((unsigned)f2bf(f1.w) << 16);
  *(uint4*)(xb + base) = o;
}

// ---------------- W[k][n] fp32 -> WT[n][k] bf16 (512x512) ----------------
__global__ void transpose_w_kernel(const float* __restrict__ W,
                                   unsigned short* __restrict__ WT) {
  __shared__ float t[32][33];
  const int tx = threadIdx.x, ty = threadIdx.y; // 32 x 8
  const int x0 = blockIdx.x * 32, y0 = blockIdx.y * 32;
#pragma unroll
  for (int r = 0; r < 4; r++)
    t[ty + 8 * r][tx] = W[(size_t)(y0 + ty + 8 * r) * DMODEL + x0 + tx];
  __syncthreads();
#pragma unroll
  for (int r = 0; r < 4; r++)
    WT[(size_t)(x0 + ty + 8 * r) * DMODEL + y0 + tx] = f2bf(t[tx][ty + 8 * r]);
}

// ---------------- GEMM 128x128 tile, BK=32, global_load_lds + XOR swizzle ---------
// C[m][n] = sum_k A[m][k]*Bt[n][k] (+bias). K=512 fixed.
// MODE 0: QK fused (Bt rows 0-511 -> out0/bias0, 512-1023 -> out1/bias1), bf16 out.
// MODE 1: V-transposed (bias by row, out stride ROWS), bf16 out.
// MODE 2: fp32 out, bias by col.
template <int MODE>
__global__ __launch_bounds__(256, 2) void gemm128_kernel(const unsigned short* __restrict__ A,
                                                         const unsigned short* __restrict__ Bt,
                                                         const float* __restrict__ bias0,
                                                         const float* __restrict__ bias1,
                                                         void* __restrict__ out0,
                                                         void* __restrict__ out1) {
  constexpr int K = DMODEL;
  __shared__ __align__(16) char smem[16384];
  char* As = smem;
  char* Bs = smem + 8192;
  const int tid = threadIdx.x;
  const int wave = tid >> 6, lane = tid & 63;
  const int wr = wave >> 1, wc = wave & 1;
  const int lm = lane & 15, lq = lane >> 4;
  const int m0 = blockIdx.y * 128, n0 = blockIdx.x * 128;
  // staging map: lane covers row lr of a 16-row group, logical chunk lc (16B).
  // HW semantics: each lane's 16B lands at readfirstlane(base)+lane*16 (m104/m108).
  const int lr = lane >> 2;
  const int lc = (lane & 3) ^ ((lane >> 3) & 3); // XOR swizzle vs physical slot lane&3
  const unsigned short* gA0 = A + (size_t)(m0 + wave * 16 + lr) * K + lc * 8;
  const unsigned short* gA1 = A + (size_t)(m0 + (wave + 4) * 16 + lr) * K + lc * 8;
  const unsigned short* gB0 = Bt + (size_t)(n0 + wave * 16 + lr) * K + lc * 8;
  const unsigned short* gB1 = Bt + (size_t)(n0 + (wave + 4) * 16 + lr) * K + lc * 8;
  char* lA0 = As + wave * 1024 + lane * 16;
  char* lA1 = As + (wave + 4) * 1024 + lane * 16;
  char* lB0 = Bs + wave * 1024 + lane * 16;
  char* lB1 = Bs + (wave + 4) * 1024 + lane * 16;
  // fragment read: physical chunk = lq ^ ((row>>1)&3), row = ...+lm
  const int sw = (lm >> 1) & 3;
  int aoff[4], boff[4];
#pragma unroll
  for (int mi = 0; mi < 4; mi++)
    aoff[mi] = (wr * 64 + mi * 16 + lm) * 64 + (lq ^ sw) * 16;
#pragma unroll
  for (int ni = 0; ni < 4; ni++)
    boff[ni] = (wc * 64 + ni * 16 + lm) * 64 + (lq ^ sw) * 16;

  f32x4 acc[4][4] = {};
  for (int k0 = 0; k0 < K; k0 += 32) {
    __syncthreads();
    glds16(gA0 + k0, lA0);
    glds16(gA1 + k0, lA1);
    glds16(gB0 + k0, lB0);
    glds16(gB1 + k0, lB1);
    __syncthreads();
    short8 af[4], bfr[4];
#pragma unroll
    for (int mi = 0; mi < 4; mi++) af[mi] = *(const short8*)(As + aoff[mi]);
#pragma unroll
    for (int ni = 0; ni < 4; ni++) bfr[ni] = *(const short8*)(Bs + boff[ni]);
#pragma unroll
    for (int mi = 0; mi < 4; mi++)
#pragma unroll
      for (int ni = 0; ni < 4; ni++)
        acc[mi][ni] = __builtin_amdgcn_mfma_f32_16x16x32_bf16(af[mi], bfr[ni], acc[mi][ni], 0, 0, 0);
  }
#pragma unroll
  for (int mi = 0; mi < 4; mi++) {
    const int row0 = m0 + wr * 64 + mi * 16 + lq * 4;
#pragma unroll
    for (int ni = 0; ni < 4; ni++) {
      const int col = n0 + wc * 64 + ni * 16 + lm;
#pragma unroll
      for (int r = 0; r < 4; r++) {
        const int row = row0 + r;
        const float v = acc[mi][ni][r];
        if (MODE == 0) {
          if (col < DMODEL)
            ((unsigned short*)out0)[(size_t)row * DMODEL + col] = f2bf(v + bias0[col]);
          else
            ((unsigned short*)out1)[(size_t)row * DMODEL + (col - DMODEL)] =
                f2bf(v + bias1[col - DMODEL]);
        } else if (MODE == 1) {
          ((unsigned short*)out0)[(size_t)row * ROWS + col] = f2bf(v + bias0[row]);
        } else {
          ((float*)out0)[(size_t)row * DMODEL + col] = v + bias0[col];
        }
      }
    }
  }
}

// ---------------- vsum[b][n] = sum_j Vt[n][b*S+j] (for all-masked fallback) -------
__global__ __launch_bounds__(256) void vsum_kernel(const unsigned short* __restrict__ Vt,
                                                   float* __restrict__ vs) {
  const int wid = blockIdx.x * 4 + (threadIdx.x >> 6);
  const int lane = threadIdx.x & 63;
  const int b = wid >> 9, n = wid & 511;
  const unsigned short* row = Vt + (size_t)n * ROWS + b * S_LEN;
  float s = 0.f;
#pragma unroll
  for (int it = 0; it < 4; it++) {
    uint4 v = *(const uint4*)(row + it * 512 + lane * 8);
    unsigned int w[4] = {v.x, v.y, v.z, v.w};
#pragma unroll
    for (int e = 0; e < 4; e++) {
      s += bf2f((unsigned short)(w[e] & 0xffffu));
      s += bf2f((unsigned short)(w[e] >> 16));
    }
  }
#pragma unroll
  for (int off = 1; off < 64; off <<= 1) s += __shfl_xor(s, off, 64);
  if (lane == 0) vs[(size_t)b * DMODEL + n] = s;
}

// ---------------- banded flash attention: 4 waves / 64 queries per block ----------
// Q,K: [B*S][512] bf16. Vt: [512][B*S] bf16. K/V tiles staged in LDS, shared by waves.
__global__ __launch_bounds__(256) void attn_kernel(const unsigned short* __restrict__ Q,
                                                   const unsigned short* __restrict__ K,
                                                   const unsigned short* __restrict__ Vt,
                                                   const int* __restrict__ x_len,
                                                   const float* __restrict__ vsum,
                                                   unsigned short* __restrict__ ctx) {
  __shared__ unsigned short Ks[32][72];     // 32 keys x 64 dims (+8 pad)
  __shared__ unsigned short Vs[64][40];     // 64 dims x 32 keys (+8 pad)
  __shared__ unsigned short Ps[4][16][40];  // per-wave P roundtrip (C-layout -> A-layout)
  const int tid = threadIdx.x;
  const int wave = tid >> 6, lane = tid & 63;
  const int lm = lane & 15, lq = lane >> 4;
  const int b = blockIdx.z, h = blockIdx.y;
  const int i0 = blockIdx.x * 64;
  const int q0 = i0 + wave * 16;
  const int xlen = x_len[b];

  const size_t qoff = (size_t)(b * S_LEN + q0 + lm) * DMODEL + h * HDIM + lq * 8;
  const short8 aq0 = *(const short8*)(Q + qoff);
  const short8 aq1 = *(const short8*)(Q + qoff + 32);

  const int krow = tid >> 3, kchk = (tid & 7) * 8; // K staging: 32 rows x 8 chunks
  const int vdim = tid >> 2, vchk = (tid & 3) * 8; // V staging: 64 dims x 4 chunks

  f32x4 oacc[4] = {};
  float mrow[4] = {-1e30f, -1e30f, -1e30f, -1e30f};
  float lrow[4] = {0.f, 0.f, 0.f, 0.f};

  for (int kt = 0; kt < 10; kt++) {
    const int jt0 = i0 - 128 + kt * 32;
    if (jt0 + 31 < 0 || jt0 >= xlen) continue; // block-uniform: tile fully masked
    __syncthreads(); // previous tile's LDS reads done
    {
      const int jr = jt0 + krow;
      const int jrc = min(max(jr, 0), S_LEN - 1);
      *(uint4*)&Ks[krow][kchk] =
          *(const uint4*)(K + (size_t)(b * S_LEN + jrc) * DMODEL + h * HDIM + kchk);
      const int jv = jt0 + vchk;
      const int jvc = min(max(jv, 0), S_LEN - 8);
      *(uint4*)&Vs[vdim][vchk] =
          *(const uint4*)(Vt + (size_t)(h * HDIM + vdim) * ROWS + b * S_LEN + jvc);
    }
    __syncthreads();
    // wave-level skip: this wave's band doesn't touch the tile
    if (jt0 + 31 < q0 - 128 || jt0 > q0 + 143) continue;

    f32x4 sv[2];
#pragma unroll
    for (int sub = 0; sub < 2; sub++) {
      const short8 bk0 = *(const short8*)&Ks[sub * 16 + lm][lq * 8];
      const short8 bk1 = *(const short8*)&Ks[sub * 16 + lm][32 + lq * 8];
      f32x4 s = {};
      s = __builtin_amdgcn_mfma_f32_16x16x32_bf16(aq0, bk0, s, 0, 0, 0);
      s = __builtin_amdgcn_mfma_f32_16x16x32_bf16(aq1, bk1, s, 0, 0, 0);
      sv[sub] = s;
    }
#pragma unroll
    for (int sub = 0; sub < 2; sub++) {
      const int j = jt0 + sub * 16 + lm;
      const bool jv = (j >= 0) && (j < xlen);
#pragma unroll
      for (int r = 0; r < 4; r++) {
        const int i = q0 + lq * 4 + r;
        const bool ok = jv && (j - i <= 128) && (i - j <= 128);
        sv[sub][r] = ok ? sv[sub][r] * 0.125f : -1e30f;
      }
    }
    float alpha[4], p0[4], p1[4];
#pragma unroll
    for (int r = 0; r < 4; r++) {
      float mx = fmaxf(sv[0][r], sv[1][r]);
#pragma unroll
      for (int off = 1; off < 16; off <<= 1) mx = fmaxf(mx, __shfl_xor(mx, off, 64));
      const float mn = fmaxf(mrow[r], mx);
      alpha[r] = __expf(mrow[r] - mn);
      mrow[r] = mn;
      p0[r] = (sv[0][r] > -1e29f) ? __expf(sv[0][r] - mn) : 0.f;
      p1[r] = (sv[1][r] > -1e29f) ? __expf(sv[1][r] - mn) : 0.f;
      float rs = p0[r] + p1[r];
#pragma unroll
      for (int off = 1; off < 16; off <<= 1) rs += __shfl_xor(rs, off, 64);
      lrow[r] = lrow[r] * alpha[r] + rs;
    }
#pragma unroll
    for (int r = 0; r < 4; r++) {
      Ps[wave][lq * 4 + r][lm] = f2bf(p0[r]);
      Ps[wave][lq * 4 + r][16 + lm] = f2bf(p1[r]);
    }
    // within-wave DS write->read: LDS pipe is in-order per wave, no barrier needed
    const short8 pf = *(const short8*)&Ps[wave][lm][lq * 8];
#pragma unroll
    for (int dt = 0; dt < 4; dt++) {
#pragma unroll
      for (int r = 0; r < 4; r++) oacc[dt][r] *= alpha[r];
      const short8 bv = *(const short8*)&Vs[dt * 16 + lm][lq * 8];
      oacc[dt] = __builtin_amdgcn_mfma_f32_16x16x32_bf16(pf, bv, oacc[dt], 0, 0, 0);
    }
  }
#pragma unroll
  for (int r = 0; r < 4; r++) {
    const int i = q0 + lq * 4 + r;
    const size_t obase = (size_t)(b * S_LEN + i) * DMODEL + h * HDIM;
    if (lrow[r] > 0.f) {
      const float inv = 1.f / lrow[r];
#pragma unroll
      for (int dt = 0; dt < 4; dt++)
        ctx[obase + dt * 16 + lm] = f2bf(oacc[dt][r] * inv);
    } else {
      // all keys masked -> reference softmax is exactly uniform over ALL 2048 keys
#pragma unroll
      for (int dt = 0; dt < 4; dt++)
        ctx[obase + dt * 16 + lm] =
            f2bf(vsum[(size_t)b * DMODEL + h * HDIM + dt * 16 + lm] * (1.f / 2048.f));
    }
  }
}

extern "C" void kernel_launch(void* const* d_in, const int* in_sizes, int n_in,
                              void* d_out, int out_size, void* d_ws, size_t ws_size,
                              hipStream_t stream) {
  (void)in_sizes; (void)n_in; (void)out_size; (void)ws_size;
  const float* x  = (const float*)d_in[0];
  const float* Wq = (const float*)d_in[1];
  const float* bq = (const float*)d_in[2];
  const float* Wk = (const float*)d_in[3];
  const float* bk = (const float*)d_in[4];
  const float* Wv = (const float*)d_in[5];
  const float* bv = (const float*)d_in[6];
  const float* Wo = (const float*)d_in[7];
  const float* bo = (const float*)d_in[8];
  const int* x_len = (const int*)d_in[9];

  char* ws = (char*)d_ws;
  const size_t MB = 1024 * 1024;
  unsigned short* xb   = (unsigned short*)(ws + 0 * MB);   // [8192][512]
  unsigned short* Qb   = (unsigned short*)(ws + 8 * MB);   // [8192][512]
  unsigned short* Kb   = (unsigned short*)(ws + 16 * MB);  // [8192][512]
  unsigned short* Vt   = (unsigned short*)(ws + 24 * MB);  // [512][8192]
  unsigned short* Cx   = (unsigned short*)(ws + 32 * MB);  // [8192][512]
  unsigned short* WqkT = (unsigned short*)(ws + 40 * MB);  // [1024][512]: Wq^T | Wk^T
  unsigned short* WvT  = (unsigned short*)(ws + 41 * MB);  // [512][512]
  unsigned short* WoT  = (unsigned short*)(ws + 41 * MB + 512 * 1024);
  float* vsum          = (float*)(ws + 42 * MB);           // [4][512]

  cvt_bf16_kernel<<<(ROWS * DMODEL) / 2048, 256, 0, stream>>>(x, xb, ROWS * DMODEL);
  dim3 tb(32, 8), tg(16, 16);
  transpose_w_kernel<<<tg, tb, 0, stream>>>(Wq, WqkT);
  transpose_w_kernel<<<tg, tb, 0, stream>>>(Wk, WqkT + 512 * 512);
  transpose_w_kernel<<<tg, tb, 0, stream>>>(Wv, WvT);
  transpose_w_kernel<<<tg, tb, 0, stream>>>(Wo, WoT);

  // Q and K in one GEMM: [8192][1024] against concatenated weights
  gemm128_kernel<0><<<dim3(8, 64), 256, 0, stream>>>(xb, WqkT, bq, bk, Qb, Kb);
  // V transposed: C[feature][row] = sum_k WvT[f][k] * xb[row][k] + bv[f]
  gemm128_kernel<1><<<dim3(64, 4), 256, 0, stream>>>(WvT, xb, bv, nullptr, Vt, nullptr);
  vsum_kernel<<<512, 256, 0, stream>>>(Vt, vsum);
  attn_kernel<<<dim3(32, 8, 4), 256, 0, stream>>>(Qb, Kb, Vt, x_len, vsum, Cx);
  // out = ctx @ Wo + bo (fp32 out)  -- FIXED: out0 = d_out (was passed as bias1!)
  gemm128_kernel<2><<<dim3(4, 64), 256, 0, stream>>>(Cx, WoT, bo, nullptr, (float*)d_out, nullptr);
}